// Round 1
// baseline (1007.828 us; speedup 1.0000x reference)
//
#include <hip/hip_runtime.h>
#include <hip/hip_bf16.h>
#include <stdint.h>

typedef __hip_bfloat16 bf16;
typedef __attribute__((ext_vector_type(8))) short bf16x8;
typedef __attribute__((ext_vector_type(4))) float f32x4;

#define MFMA16(a,b,c) __builtin_amdgcn_mfma_f32_16x16x32_bf16((a),(b),(c),0,0,0)

#define BATCH 2
#define S_LEN 2048
#define HID_D 2048
#define NHEAD 16
#define QLR_D 1536
#define KVLR_D 512
#define DN_D 128
#define DR_D 64
#define DV_D 128
// 1/sqrt(192)
#define ATT_SCALE 0.07216878364870322f

__device__ __forceinline__ void async_load16(const bf16* g, bf16* l) {
    __builtin_amdgcn_global_load_lds((const __attribute__((address_space(1))) uint32_t*)g,
                                     (__attribute__((address_space(3))) uint32_t*)l,
                                     16, 0, 0);
}

__device__ __forceinline__ unsigned short f2bf_bits(float f) {
    bf16 h = __float2bfloat16(f);
    return *reinterpret_cast<unsigned short*>(&h);
}

// ---------------- elementwise fp32 -> bf16 convert ----------------
__global__ void convert_bf16_kernel(const float* __restrict__ in, bf16* __restrict__ out, int n) {
    int idx = blockIdx.x * blockDim.x + threadIdx.x;
    int i4 = idx * 4;
    if (i4 >= n) return;
    float4 v = *(const float4*)(in + i4);
    ushort4 o;
    o.x = f2bf_bits(v.x);
    o.y = f2bf_bits(v.y);
    o.z = f2bf_bits(v.z);
    o.w = f2bf_bits(v.w);
    *(ushort4*)(out + i4) = o;
}

// ---------------- transpose + convert: in (K x N) fp32 -> out (N x K) bf16 ----------------
__global__ void transpose_convert_kernel(const float* __restrict__ in, bf16* __restrict__ out,
                                         int K, int N) {
    __shared__ float tile[32][33];
    int tx = threadIdx.x;   // 0..31
    int ty = threadIdx.y;   // 0..7
    int n0 = blockIdx.x * 32, k0 = blockIdx.y * 32;
#pragma unroll
    for (int i = 0; i < 4; i++)
        tile[ty + i * 8][tx] = in[(size_t)(k0 + ty + i * 8) * N + n0 + tx];
    __syncthreads();
#pragma unroll
    for (int i = 0; i < 4; i++)
        out[(size_t)(n0 + ty + i * 8) * K + k0 + tx] = __float2bfloat16(tile[tx][ty + i * 8]);
}

// ---------------- GEMM: C(MxN) = A(MxK,row) * Bt(NxK,row)^T ; bf16 in, CT out ----------------
template <typename CT>
__global__ __launch_bounds__(256, 2)
void gemm_bt_kernel(const bf16* __restrict__ A, const bf16* __restrict__ Bt,
                    CT* __restrict__ C, int M, int N, int K) {
    __shared__ __align__(16) bf16 As[128 * 64];
    __shared__ __align__(16) bf16 Bs[128 * 64];
    const int tid = threadIdx.x;
    const int wave = tid >> 6, lane = tid & 63;
    const int quad = lane >> 4, l16 = lane & 15;
    const int wm = (wave >> 1) * 64, wn = (wave & 1) * 64;
    const int m0 = blockIdx.y * 128, n0 = blockIdx.x * 128;

    f32x4 acc[4][4];
#pragma unroll
    for (int i = 0; i < 4; i++)
#pragma unroll
        for (int j = 0; j < 4; j++)
            acc[i][j] = (f32x4){0.f, 0.f, 0.f, 0.f};

    const bf16* ga = A + (size_t)m0 * K;
    const bf16* gb = Bt + (size_t)n0 * K;

    for (int k0 = 0; k0 < K; k0 += 64) {
        __syncthreads();
        // stage 128x64 A-tile and B-tile; 4 issues x 256 threads x 16B each
#pragma unroll
        for (int i = 0; i < 4; i++) {
            int chunk = i * 256 + tid;          // per-lane
            int row = chunk >> 3, cseg = chunk & 7;
            int wbase = i * 256 + wave * 64;    // wave-uniform LDS base chunk
            async_load16(ga + (size_t)row * K + k0 + cseg * 8, &As[wbase * 8]);
            async_load16(gb + (size_t)row * K + k0 + cseg * 8, &Bs[wbase * 8]);
        }
        __syncthreads();
#pragma unroll
        for (int kk = 0; kk < 64; kk += 32) {
            bf16x8 af[4], bfr[4];
#pragma unroll
            for (int t = 0; t < 4; t++) {
                af[t]  = *(const bf16x8*)&As[(wm + t * 16 + l16) * 64 + kk + quad * 8];
                bfr[t] = *(const bf16x8*)&Bs[(wn + t * 16 + l16) * 64 + kk + quad * 8];
            }
#pragma unroll
            for (int tm = 0; tm < 4; tm++)
#pragma unroll
                for (int tn = 0; tn < 4; tn++)
                    acc[tm][tn] = MFMA16(af[tm], bfr[tn], acc[tm][tn]);
        }
    }
    // epilogue: C/D layout col=lane&15, row=quad*4+reg
#pragma unroll
    for (int tm = 0; tm < 4; tm++)
#pragma unroll
        for (int tn = 0; tn < 4; tn++)
#pragma unroll
            for (int r = 0; r < 4; r++) {
                int row = m0 + wm + tm * 16 + quad * 4 + r;
                int col = n0 + wn + tn * 16 + l16;
                float v = acc[tm][tn][r];
                if constexpr (sizeof(CT) == 2)
                    ((bf16*)C)[(size_t)row * N + col] = __float2bfloat16(v);
                else
                    ((float*)C)[(size_t)row * N + col] = v;
            }
}

// ---------------- RoPE (in-place on bf16 buffer laid out (rows, NH*64)) ----------------
__global__ void rope_kernel(bf16* __restrict__ buf, int nrows) {
    int idx = blockIdx.x * blockDim.x + threadIdx.x;
    if (idx >= nrows * NHEAD * 32) return;
    int j = idx & 31;
    int h = (idx >> 5) & (NHEAD - 1);
    int row = idx >> 9;          // / (16*32)
    int pos = row & (S_LEN - 1); // row = b*S + s
    float inv = powf(10000.f, -(float)j / 32.f);
    float f = (float)pos * inv;
    float c = cosf(f), s = sinf(f);
    bf16* p = buf + (size_t)row * (NHEAD * DR_D) + h * DR_D + j;
    float x1 = __bfloat162float(p[0]);
    float x2 = __bfloat162float(p[32]);
    p[0]  = __float2bfloat16(x1 * c - x2 * s);
    p[32] = __float2bfloat16(x2 * c + x1 * s);
}

// ---------------- flash attention: per block one (q-tile of 64, b*NH) ----------------
__global__ __launch_bounds__(256, 2)
void attn_kernel(const bf16* __restrict__ qn, const bf16* __restrict__ qr,
                 const bf16* __restrict__ kn, const bf16* __restrict__ kr,
                 const bf16* __restrict__ vv, bf16* __restrict__ o_out) {
    __shared__ __align__(16) bf16 q_s[64 * 192];
    __shared__ __align__(16) bf16 k_s[64 * 192];
    __shared__ __align__(16) bf16 vt_s[128 * 64];   // (dv, kv)
    __shared__ __align__(16) bf16 p_s[4 * 16 * 64]; // per wave 16x64

    const int tid = threadIdx.x;
    const int wave = tid >> 6, lane = tid & 63;
    const int quad = lane >> 4, l16 = lane & 15;
    const int q0 = blockIdx.x * 64;
    const int bh = blockIdx.y;
    const int b = bh >> 4, h = bh & 15;
    const size_t tokbase = (size_t)b * S_LEN;

    // load Q tile: 64 rows x 192 (128 nope + 64 rope)
    for (int i = tid; i < 64 * 24; i += 256) {
        int row = i / 24, seg = i % 24;
        const bf16* src = (seg < 16)
            ? qn + (tokbase + q0 + row) * (NHEAD * DN_D) + h * DN_D + seg * 8
            : qr + (tokbase + q0 + row) * (NHEAD * DR_D) + h * DR_D + (seg - 16) * 8;
        *(uint4*)&q_s[row * 192 + seg * 8] = *(const uint4*)src;
    }

    float m_run[4], l_run[4];
#pragma unroll
    for (int r = 0; r < 4; r++) { m_run[r] = -1e30f; l_run[r] = 0.f; }
    f32x4 oacc[8];
#pragma unroll
    for (int i = 0; i < 8; i++) oacc[i] = (f32x4){0.f, 0.f, 0.f, 0.f};

    for (int kv0 = 0; kv0 <= q0 + 63; kv0 += 64) {
        __syncthreads();
        // load K chunk (64x192)
        for (int i = tid; i < 64 * 24; i += 256) {
            int row = i / 24, seg = i % 24;
            const bf16* src = (seg < 16)
                ? kn + (tokbase + kv0 + row) * (NHEAD * DN_D) + h * DN_D + seg * 8
                : kr + (tokbase + kv0 + row) * (NHEAD * DR_D) + h * DR_D + (seg - 16) * 8;
            *(uint4*)&k_s[row * 192 + seg * 8] = *(const uint4*)src;
        }
        // load V chunk transposed: vt_s[dv][kv]
        for (int i = tid; i < 64 * 16; i += 256) {
            int row = i / 16, seg = i % 16;
            uint4 d = *(const uint4*)(vv + (tokbase + kv0 + row) * (NHEAD * DV_D) + h * DV_D + seg * 8);
            const bf16* e = (const bf16*)&d;
#pragma unroll
            for (int j = 0; j < 8; j++) vt_s[(seg * 8 + j) * 64 + row] = e[j];
        }
        __syncthreads();

        if (kv0 <= q0 + wave * 16 + 15) {   // wave-uniform
            // S = Q K^T  (16 x 64 per wave)
            f32x4 sa[4];
#pragma unroll
            for (int nt = 0; nt < 4; nt++) sa[nt] = (f32x4){0.f, 0.f, 0.f, 0.f};
#pragma unroll
            for (int kk = 0; kk < 192; kk += 32) {
                bf16x8 aq = *(const bf16x8*)&q_s[(wave * 16 + l16) * 192 + kk + quad * 8];
#pragma unroll
                for (int nt = 0; nt < 4; nt++) {
                    bf16x8 bk = *(const bf16x8*)&k_s[(nt * 16 + l16) * 192 + kk + quad * 8];
                    sa[nt] = MFMA16(aq, bk, sa[nt]);
                }
            }
            // online softmax over this 16x64 block
            float pval[4][4], alpha[4];
#pragma unroll
            for (int r = 0; r < 4; r++) {
                int qpos = q0 + wave * 16 + quad * 4 + r;
                float mx = -1e30f;
#pragma unroll
                for (int nt = 0; nt < 4; nt++) {
                    int kvpos = kv0 + nt * 16 + l16;
                    float sv = (kvpos <= qpos) ? sa[nt][r] * ATT_SCALE : -1e30f;
                    pval[nt][r] = sv;
                    mx = fmaxf(mx, sv);
                }
#pragma unroll
                for (int off = 1; off < 16; off <<= 1) mx = fmaxf(mx, __shfl_xor(mx, off, 64));
                float mnew = fmaxf(m_run[r], mx);
                float rs = 0.f;
#pragma unroll
                for (int nt = 0; nt < 4; nt++) {
                    float p = __expf(pval[nt][r] - mnew);
                    pval[nt][r] = p;
                    rs += p;
                }
#pragma unroll
                for (int off = 1; off < 16; off <<= 1) rs += __shfl_xor(rs, off, 64);
                alpha[r] = __expf(m_run[r] - mnew);
                l_run[r] = alpha[r] * l_run[r] + rs;
                m_run[r] = mnew;
            }
            // P -> LDS (A-layout staging)
#pragma unroll
            for (int r = 0; r < 4; r++)
#pragma unroll
                for (int nt = 0; nt < 4; nt++)
                    p_s[wave * 1024 + (quad * 4 + r) * 64 + nt * 16 + l16] =
                        __float2bfloat16(pval[nt][r]);
            // rescale O
#pragma unroll
            for (int d = 0; d < 8; d++)
#pragma unroll
                for (int r = 0; r < 4; r++) oacc[d][r] *= alpha[r];
            // O += P V
#pragma unroll
            for (int kk = 0; kk < 64; kk += 32) {
                bf16x8 ap = *(const bf16x8*)&p_s[wave * 1024 + l16 * 64 + kk + quad * 8];
#pragma unroll
                for (int d = 0; d < 8; d++) {
                    bf16x8 bv = *(const bf16x8*)&vt_s[(d * 16 + l16) * 64 + kk + quad * 8];
                    oacc[d] = MFMA16(ap, bv, oacc[d]);
                }
            }
        }
    }
    // epilogue
#pragma unroll
    for (int d = 0; d < 8; d++)
#pragma unroll
        for (int r = 0; r < 4; r++) {
            int qrow = q0 + wave * 16 + quad * 4 + r;
            int col = h * DV_D + d * 16 + l16;
            o_out[(tokbase + qrow) * (NHEAD * DV_D) + col] =
                __float2bfloat16(oacc[d][r] / l_run[r]);
        }
}

// ---------------- launch ----------------
extern "C" void kernel_launch(void* const* d_in, const int* in_sizes, int n_in,
                              void* d_out, int out_size, void* d_ws, size_t ws_size,
                              hipStream_t stream) {
    const float* hs        = (const float*)d_in[0];
    const float* w_q_a     = (const float*)d_in[2];
    const float* w_q_nope  = (const float*)d_in[3];
    const float* w_q_rope  = (const float*)d_in[4];
    const float* w_kv_a    = (const float*)d_in[5];
    const float* w_k_nope  = (const float*)d_in[6];
    const float* w_k_rope  = (const float*)d_in[7];
    const float* w_v       = (const float*)d_in[8];
    const float* w_o       = (const float*)d_in[9];
    float* out = (float*)d_out;

    const int M = BATCH * S_LEN;  // 4096

    char* wsp = (char*)d_ws;
    auto alloc = [&](size_t elems) {
        bf16* p = (bf16*)wsp;
        wsp += ((elems * 2 + 255) / 256) * 256;
        return p;
    };
    bf16* hs_b   = alloc((size_t)M * HID_D);
    bf16* wqa_t  = alloc((size_t)QLR_D * HID_D);
    bf16* wkva_t = alloc((size_t)KVLR_D * HID_D);
    bf16* wqn_t  = alloc((size_t)(NHEAD * DN_D) * QLR_D);
    bf16* wqr_t  = alloc((size_t)(NHEAD * DR_D) * QLR_D);
    bf16* wkn_t  = alloc((size_t)(NHEAD * DN_D) * KVLR_D);
    bf16* wkr_t  = alloc((size_t)(NHEAD * DR_D) * KVLR_D);
    bf16* wv_t   = alloc((size_t)(NHEAD * DV_D) * KVLR_D);
    bf16* wo_t   = alloc((size_t)HID_D * (NHEAD * DV_D));
    bf16* q_c    = alloc((size_t)M * QLR_D);
    bf16* kv_c   = alloc((size_t)M * KVLR_D);
    bf16* q_nope = alloc((size_t)M * NHEAD * DN_D);
    bf16* q_rope = alloc((size_t)M * NHEAD * DR_D);
    bf16* k_nope = alloc((size_t)M * NHEAD * DN_D);
    bf16* k_rope = alloc((size_t)M * NHEAD * DR_D);
    bf16* v_buf  = alloc((size_t)M * NHEAD * DV_D);
    bf16* a_out  = alloc((size_t)M * NHEAD * DV_D);

    // convert hidden states
    {
        int n = M * HID_D;
        convert_bf16_kernel<<<(n / 4 + 255) / 256, 256, 0, stream>>>(hs, hs_b, n);
    }
    // transpose-convert weights: in (K,N) -> out (N,K)
    dim3 tb(32, 8);
    transpose_convert_kernel<<<dim3(QLR_D / 32, HID_D / 32), tb, 0, stream>>>(w_q_a, wqa_t, HID_D, QLR_D);
    transpose_convert_kernel<<<dim3(KVLR_D / 32, HID_D / 32), tb, 0, stream>>>(w_kv_a, wkva_t, HID_D, KVLR_D);
    transpose_convert_kernel<<<dim3((NHEAD * DN_D) / 32, QLR_D / 32), tb, 0, stream>>>(w_q_nope, wqn_t, QLR_D, NHEAD * DN_D);
    transpose_convert_kernel<<<dim3((NHEAD * DR_D) / 32, QLR_D / 32), tb, 0, stream>>>(w_q_rope, wqr_t, QLR_D, NHEAD * DR_D);
    transpose_convert_kernel<<<dim3((NHEAD * DN_D) / 32, KVLR_D / 32), tb, 0, stream>>>(w_k_nope, wkn_t, KVLR_D, NHEAD * DN_D);
    transpose_convert_kernel<<<dim3((NHEAD * DR_D) / 32, KVLR_D / 32), tb, 0, stream>>>(w_k_rope, wkr_t, KVLR_D, NHEAD * DR_D);
    transpose_convert_kernel<<<dim3((NHEAD * DV_D) / 32, KVLR_D / 32), tb, 0, stream>>>(w_v, wv_t, KVLR_D, NHEAD * DV_D);
    transpose_convert_kernel<<<dim3(HID_D / 32, (NHEAD * DV_D) / 32), tb, 0, stream>>>(w_o, wo_t, NHEAD * DV_D, HID_D);

    // projections
    gemm_bt_kernel<bf16><<<dim3(QLR_D / 128, M / 128), 256, 0, stream>>>(hs_b, wqa_t, q_c, M, QLR_D, HID_D);
    gemm_bt_kernel<bf16><<<dim3(KVLR_D / 128, M / 128), 256, 0, stream>>>(hs_b, wkva_t, kv_c, M, KVLR_D, HID_D);
    gemm_bt_kernel<bf16><<<dim3((NHEAD * DN_D) / 128, M / 128), 256, 0, stream>>>(q_c, wqn_t, q_nope, M, NHEAD * DN_D, QLR_D);
    gemm_bt_kernel<bf16><<<dim3((NHEAD * DR_D) / 128, M / 128), 256, 0, stream>>>(q_c, wqr_t, q_rope, M, NHEAD * DR_D, QLR_D);
    gemm_bt_kernel<bf16><<<dim3((NHEAD * DN_D) / 128, M / 128), 256, 0, stream>>>(kv_c, wkn_t, k_nope, M, NHEAD * DN_D, KVLR_D);
    gemm_bt_kernel<bf16><<<dim3((NHEAD * DR_D) / 128, M / 128), 256, 0, stream>>>(kv_c, wkr_t, k_rope, M, NHEAD * DR_D, KVLR_D);
    gemm_bt_kernel<bf16><<<dim3((NHEAD * DV_D) / 128, M / 128), 256, 0, stream>>>(kv_c, wv_t, v_buf, M, NHEAD * DV_D, KVLR_D);

    // rope on q_rope, k_rope
    {
        int n = M * NHEAD * 32;
        rope_kernel<<<(n + 255) / 256, 256, 0, stream>>>(q_rope, M);
        rope_kernel<<<(n + 255) / 256, 256, 0, stream>>>(k_rope, M);
    }

    // attention
    attn_kernel<<<dim3(S_LEN / 64, BATCH * NHEAD), 256, 0, stream>>>(q_nope, q_rope, k_nope, k_rope, v_buf, a_out);

    // output projection (fp32 out)
    gemm_bt_kernel<float><<<dim3(HID_D / 128, M / 128), 256, 0, stream>>>(a_out, wo_t, out, M, HID_D, NHEAD * DV_D);

    (void)in_sizes; (void)n_in; (void)out_size; (void)ws_size;
}

// Round 2
// 620.526 us; speedup vs baseline: 1.6242x; 1.6242x over previous
//
#include <hip/hip_runtime.h>
#include <hip/hip_bf16.h>
#include <stdint.h>

typedef __hip_bfloat16 bf16;
typedef __attribute__((ext_vector_type(8))) short bf16x8;
typedef __attribute__((ext_vector_type(4))) float f32x4;

#define MFMA16(a,b,c) __builtin_amdgcn_mfma_f32_16x16x32_bf16((a),(b),(c),0,0,0)

#define BATCH 2
#define S_LEN 2048
#define HID_D 2048
#define NHEAD 16
#define QLR_D 1536
#define KVLR_D 512
#define DN_D 128
#define DR_D 64
#define DV_D 128
#define QKD 192            // DN + DR
// 1/sqrt(192)
#define ATT_SCALE 0.07216878364870322f

__device__ __forceinline__ void async_load16(const bf16* g, bf16* l) {
    __builtin_amdgcn_global_load_lds((const __attribute__((address_space(1))) uint32_t*)g,
                                     (__attribute__((address_space(3))) uint32_t*)l,
                                     16, 0, 0);
}

__device__ __forceinline__ unsigned short f2bf_bits(float f) {
    bf16 h = __float2bfloat16(f);
    return *reinterpret_cast<unsigned short*>(&h);
}

// ---------------- elementwise fp32 -> bf16 convert ----------------
__global__ void convert_bf16_kernel(const float* __restrict__ in, bf16* __restrict__ out, int n) {
    int idx = blockIdx.x * blockDim.x + threadIdx.x;
    int i4 = idx * 4;
    if (i4 >= n) return;
    float4 v = *(const float4*)(in + i4);
    ushort4 o;
    o.x = f2bf_bits(v.x);
    o.y = f2bf_bits(v.y);
    o.z = f2bf_bits(v.z);
    o.w = f2bf_bits(v.w);
    *(ushort4*)(out + i4) = o;
}

// ---------------- transpose + convert: in (K x N) fp32 -> out (N x K) bf16 ----------------
__global__ void transpose_convert_kernel(const float* __restrict__ in, bf16* __restrict__ out,
                                         int K, int N) {
    __shared__ float tile[32][33];
    int tx = threadIdx.x;   // 0..31
    int ty = threadIdx.y;   // 0..7
    int n0 = blockIdx.x * 32, k0 = blockIdx.y * 32;
#pragma unroll
    for (int i = 0; i < 4; i++)
        tile[ty + i * 8][tx] = in[(size_t)(k0 + ty + i * 8) * N + n0 + tx];
    __syncthreads();
#pragma unroll
    for (int i = 0; i < 4; i++)
        out[(size_t)(n0 + ty + i * 8) * K + k0 + tx] = __float2bfloat16(tile[tx][ty + i * 8]);
}

// ---------------- GEMM: C(MxN) = A(MxK,row) * Bt(NxK,row)^T ----------------
// MODE 0: bf16 row-major (ld=N). MODE 1: fp32 row-major. MODE 2: bf16 head-remap
// (col -> h*192 + p1 + (col & ((1<<p0)-1)), h = col>>p0, ld = NHEAD*192).
// MODE 3: bf16 transposed (C[col*M + row], vectorized 4-row store).
template <int MODE>
__global__ __launch_bounds__(256, 2)
void gemm_bt_kernel(const bf16* __restrict__ A, const bf16* __restrict__ Bt,
                    void* __restrict__ C, int M, int N, int K, int p0, int p1) {
    __shared__ __align__(16) bf16 As[128 * 64];
    __shared__ __align__(16) bf16 Bs[128 * 64];
    const int tid = threadIdx.x;
    const int wave = tid >> 6, lane = tid & 63;
    const int quad = lane >> 4, l16 = lane & 15;
    const int wm = (wave >> 1) * 64, wn = (wave & 1) * 64;
    const int m0 = blockIdx.y * 128, n0 = blockIdx.x * 128;

    f32x4 acc[4][4];
#pragma unroll
    for (int i = 0; i < 4; i++)
#pragma unroll
        for (int j = 0; j < 4; j++)
            acc[i][j] = (f32x4){0.f, 0.f, 0.f, 0.f};

    const bf16* ga = A + (size_t)m0 * K;
    const bf16* gb = Bt + (size_t)n0 * K;

    for (int k0 = 0; k0 < K; k0 += 64) {
        __syncthreads();
#pragma unroll
        for (int i = 0; i < 4; i++) {
            int chunk = i * 256 + tid;
            int row = chunk >> 3, cseg = chunk & 7;
            int wbase = i * 256 + wave * 64;
            async_load16(ga + (size_t)row * K + k0 + cseg * 8, &As[wbase * 8]);
            async_load16(gb + (size_t)row * K + k0 + cseg * 8, &Bs[wbase * 8]);
        }
        __syncthreads();
#pragma unroll
        for (int kk = 0; kk < 64; kk += 32) {
            bf16x8 af[4], bfr[4];
#pragma unroll
            for (int t = 0; t < 4; t++) {
                af[t]  = *(const bf16x8*)&As[(wm + t * 16 + l16) * 64 + kk + quad * 8];
                bfr[t] = *(const bf16x8*)&Bs[(wn + t * 16 + l16) * 64 + kk + quad * 8];
            }
#pragma unroll
            for (int tm = 0; tm < 4; tm++)
#pragma unroll
                for (int tn = 0; tn < 4; tn++)
                    acc[tm][tn] = MFMA16(af[tm], bfr[tn], acc[tm][tn]);
        }
    }
    // epilogue: C/D layout col=lane&15, row=quad*4+reg
#pragma unroll
    for (int tm = 0; tm < 4; tm++)
#pragma unroll
        for (int tn = 0; tn < 4; tn++) {
            int col = n0 + wn + tn * 16 + l16;
            if constexpr (MODE == 3) {
                int row0 = m0 + wm + tm * 16 + quad * 4;
                ushort4 pk;
                pk.x = f2bf_bits(acc[tm][tn][0]);
                pk.y = f2bf_bits(acc[tm][tn][1]);
                pk.z = f2bf_bits(acc[tm][tn][2]);
                pk.w = f2bf_bits(acc[tm][tn][3]);
                *(ushort4*)((bf16*)C + (size_t)col * M + row0) = pk;
            } else {
#pragma unroll
                for (int r = 0; r < 4; r++) {
                    int row = m0 + wm + tm * 16 + quad * 4 + r;
                    float v = acc[tm][tn][r];
                    if constexpr (MODE == 0)
                        ((bf16*)C)[(size_t)row * N + col] = __float2bfloat16(v);
                    else if constexpr (MODE == 1)
                        ((float*)C)[(size_t)row * N + col] = v;
                    else {  // MODE 2
                        int hh = col >> p0, dd = col & ((1 << p0) - 1);
                        ((bf16*)C)[(size_t)row * (NHEAD * QKD) + hh * QKD + p1 + dd] =
                            __float2bfloat16(v);
                    }
                }
            }
        }
}

// ---------------- RoPE in-place on fused (M, NH, 192) buffer, cols 128..191 ----------------
__global__ void rope_kernel(bf16* __restrict__ buf, int nrows) {
    int idx = blockIdx.x * blockDim.x + threadIdx.x;
    if (idx >= nrows * NHEAD * 32) return;
    int j = idx & 31;
    int h = (idx >> 5) & (NHEAD - 1);
    int row = idx >> 9;          // / (16*32)
    int pos = row & (S_LEN - 1); // row = b*S + s
    float inv = __expf(-(float)j * (9.210340371976184f / 32.f));  // ln(10000)/32
    float f = (float)pos * inv;
    float c = __cosf(f), s = __sinf(f);
    bf16* p = buf + (size_t)row * (NHEAD * QKD) + h * QKD + 128 + j;
    float x1 = __bfloat162float(p[0]);
    float x2 = __bfloat162float(p[32]);
    p[0]  = __float2bfloat16(x1 * c - x2 * s);
    p[32] = __float2bfloat16(x2 * c + x1 * s);
}

// ---------------- flash attention v2: 128 q-rows/block, Q in regs, async K/V^T staging ---
__global__ __launch_bounds__(256, 2)
void attn_kernel(const bf16* __restrict__ qf_g, const bf16* __restrict__ kf_g,
                 const bf16* __restrict__ vT, bf16* __restrict__ o_out) {
    __shared__ __align__(16) bf16 k_s[64 * QKD];     // 24 KB
    __shared__ __align__(16) bf16 vt_s[128 * 64];    // 16 KB  (d, kv)
    __shared__ __align__(16) bf16 p_s[4 * 32 * 64];  // 16 KB  per-wave 32x64, quad-XOR swizzled

    const int tid = threadIdx.x;
    const int wave = tid >> 6, lane = tid & 63;
    const int quad = lane >> 4, l16 = lane & 15;
    const int qt = gridDim.x - 1 - blockIdx.x;   // longest-first
    const int q0 = qt * 128;
    const int bh = blockIdx.y;
    const int b = bh >> 4, h = bh & 15;
    const int tokbase = b * S_LEN;
    const int M = BATCH * S_LEN;

    // Q fragments in registers: 2 row-tiles x 6 k-chunks
    const int wq = q0 + wave * 32;
    bf16x8 qfr[2][6];
#pragma unroll
    for (int mt = 0; mt < 2; mt++) {
        const bf16* qrow = qf_g + (size_t)(tokbase + wq + mt * 16 + l16) * (NHEAD * QKD)
                                + h * QKD + quad * 8;
#pragma unroll
        for (int kk = 0; kk < 6; kk++)
            qfr[mt][kk] = *(const bf16x8*)(qrow + kk * 32);
    }

    float m_run[2][4], l_run[2][4];
#pragma unroll
    for (int mt = 0; mt < 2; mt++)
#pragma unroll
        for (int r = 0; r < 4; r++) { m_run[mt][r] = -1e30f; l_run[mt][r] = 0.f; }
    f32x4 oacc[2][8];
#pragma unroll
    for (int mt = 0; mt < 2; mt++)
#pragma unroll
        for (int d = 0; d < 8; d++) oacc[mt][d] = (f32x4){0.f, 0.f, 0.f, 0.f};

    const int niter = q0 / 64 + 2;
    for (int it = 0; it < niter; it++) {
        const int kv0 = it * 64;
        __syncthreads();
        // stage K tile: 64 rows x 192 = 1536 16B-chunks, 6 issues
#pragma unroll
        for (int i = 0; i < 6; i++) {
            int c = i * 256 + tid;
            int row = c / 24, seg = c % 24;
            async_load16(kf_g + (size_t)(tokbase + kv0 + row) * (NHEAD * QKD) + h * QKD + seg * 8,
                         &k_s[(i * 256 + wave * 64) * 8]);
        }
        // stage V^T tile: 128 d-rows x 64 kv = 1024 chunks, 4 issues
#pragma unroll
        for (int i = 0; i < 4; i++) {
            int c = i * 256 + tid;
            int d = c >> 3, seg = c & 7;
            async_load16(vT + (size_t)(h * 128 + d) * M + tokbase + kv0 + seg * 8,
                         &vt_s[(i * 256 + wave * 64) * 8]);
        }
        __syncthreads();

        if (kv0 <= wq + 31) {
            const bool do0 = kv0 <= wq + 15;  // mt=0 tile not fully masked
            // S = Q K^T : 2 x (16 x 64)
            f32x4 sa[2][4];
#pragma unroll
            for (int mt = 0; mt < 2; mt++)
#pragma unroll
                for (int nt = 0; nt < 4; nt++) sa[mt][nt] = (f32x4){0.f, 0.f, 0.f, 0.f};
#pragma unroll
            for (int kk = 0; kk < 6; kk++) {
                bf16x8 bk[4];
#pragma unroll
                for (int nt = 0; nt < 4; nt++)
                    bk[nt] = *(const bf16x8*)&k_s[(nt * 16 + l16) * QKD + kk * 32 + quad * 8];
#pragma unroll
                for (int mt = 0; mt < 2; mt++)
#pragma unroll
                    for (int nt = 0; nt < 4; nt++)
                        sa[mt][nt] = MFMA16(qfr[mt][kk], bk[nt], sa[mt][nt]);
            }

            // online softmax + P store (per row-tile)
            auto softmax_mt = [&](int mt) {
                const int qmin = wq + mt * 16;
                const bool needMask = (kv0 + 63) > qmin;
                float alpha[4];
#pragma unroll
                for (int r = 0; r < 4; r++) {
                    const int qpos = qmin + quad * 4 + r;
                    float mx = m_run[mt][r];
                    float sv[4];
#pragma unroll
                    for (int nt = 0; nt < 4; nt++) {
                        float x = sa[mt][nt][r];
                        if (needMask && (kv0 + nt * 16 + l16 > qpos)) x = -1e30f;
                        sv[nt] = x;
                        mx = fmaxf(mx, x);
                    }
                    mx = fmaxf(mx, __shfl_xor(mx, 1, 64));
                    mx = fmaxf(mx, __shfl_xor(mx, 2, 64));
                    mx = fmaxf(mx, __shfl_xor(mx, 4, 64));
                    mx = fmaxf(mx, __shfl_xor(mx, 8, 64));
                    float rs = 0.f;
#pragma unroll
                    for (int nt = 0; nt < 4; nt++) {
                        float p = __expf(ATT_SCALE * (sv[nt] - mx));
                        sv[nt] = p;
                        rs += p;
                    }
                    rs += __shfl_xor(rs, 1, 64);
                    rs += __shfl_xor(rs, 2, 64);
                    rs += __shfl_xor(rs, 4, 64);
                    rs += __shfl_xor(rs, 8, 64);
                    alpha[r] = __expf(ATT_SCALE * (m_run[mt][r] - mx));
                    l_run[mt][r] = alpha[r] * l_run[mt][r] + rs;
                    m_run[mt][r] = mx;
                    // store P, quad-XOR swizzle on 16-col groups (conflict-free)
                    const int row = mt * 16 + quad * 4 + r;
#pragma unroll
                    for (int nt = 0; nt < 4; nt++)
                        p_s[wave * 2048 + row * 64 + ((nt ^ quad) << 4) + l16] =
                            __float2bfloat16(sv[nt]);
                }
#pragma unroll
                for (int d = 0; d < 8; d++)
#pragma unroll
                    for (int r = 0; r < 4; r++) oacc[mt][d][r] *= alpha[r];
            };
            if (do0) softmax_mt(0);
            softmax_mt(1);

            // O += P V : A-frags from swizzled p_s, B-frags from vt_s
#pragma unroll
            for (int kk = 0; kk < 2; kk++) {
                bf16x8 bv[8];
#pragma unroll
                for (int d = 0; d < 8; d++)
                    bv[d] = *(const bf16x8*)&vt_s[(d * 16 + l16) * 64 + kk * 32 + quad * 8];
                const int grp = (kk * 2 + (quad >> 1)) ^ (l16 >> 2);
                const int lo8 = (quad & 1) * 8;
                bf16x8 ap1 = *(const bf16x8*)&p_s[wave * 2048 + (16 + l16) * 64 + (grp << 4) + lo8];
                if (do0) {
                    bf16x8 ap0 = *(const bf16x8*)&p_s[wave * 2048 + l16 * 64 + (grp << 4) + lo8];
#pragma unroll
                    for (int d = 0; d < 8; d++) oacc[0][d] = MFMA16(ap0, bv[d], oacc[0][d]);
                }
#pragma unroll
                for (int d = 0; d < 8; d++) oacc[1][d] = MFMA16(ap1, bv[d], oacc[1][d]);
            }
        }
    }

    // epilogue: divide by l, write (M, NH*128) bf16
#pragma unroll
    for (int mt = 0; mt < 2; mt++)
#pragma unroll
        for (int d = 0; d < 8; d++)
#pragma unroll
            for (int r = 0; r < 4; r++) {
                int qrow = wq + mt * 16 + quad * 4 + r;
                int col = h * DV_D + d * 16 + l16;
                o_out[(size_t)(tokbase + qrow) * (NHEAD * DV_D) + col] =
                    __float2bfloat16(oacc[mt][d][r] / l_run[mt][r]);
            }
}

// ---------------- launch ----------------
extern "C" void kernel_launch(void* const* d_in, const int* in_sizes, int n_in,
                              void* d_out, int out_size, void* d_ws, size_t ws_size,
                              hipStream_t stream) {
    const float* hs        = (const float*)d_in[0];
    const float* w_q_a     = (const float*)d_in[2];
    const float* w_q_nope  = (const float*)d_in[3];
    const float* w_q_rope  = (const float*)d_in[4];
    const float* w_kv_a    = (const float*)d_in[5];
    const float* w_k_nope  = (const float*)d_in[6];
    const float* w_k_rope  = (const float*)d_in[7];
    const float* w_v       = (const float*)d_in[8];
    const float* w_o       = (const float*)d_in[9];
    float* out = (float*)d_out;

    const int M = BATCH * S_LEN;  // 4096

    char* wsp = (char*)d_ws;
    auto alloc = [&](size_t elems) {
        bf16* p = (bf16*)wsp;
        wsp += ((elems * 2 + 255) / 256) * 256;
        return p;
    };
    bf16* hs_b   = alloc((size_t)M * HID_D);
    bf16* wqa_t  = alloc((size_t)QLR_D * HID_D);
    bf16* wkva_t = alloc((size_t)KVLR_D * HID_D);
    bf16* wqn_t  = alloc((size_t)(NHEAD * DN_D) * QLR_D);
    bf16* wqr_t  = alloc((size_t)(NHEAD * DR_D) * QLR_D);
    bf16* wkn_t  = alloc((size_t)(NHEAD * DN_D) * KVLR_D);
    bf16* wkr_t  = alloc((size_t)(NHEAD * DR_D) * KVLR_D);
    bf16* wv_t   = alloc((size_t)(NHEAD * DV_D) * KVLR_D);
    bf16* wo_t   = alloc((size_t)HID_D * (NHEAD * DV_D));
    bf16* q_c    = alloc((size_t)M * QLR_D);
    bf16* kv_c   = alloc((size_t)M * KVLR_D);
    bf16* q_full = alloc((size_t)M * NHEAD * QKD);
    bf16* k_full = alloc((size_t)M * NHEAD * QKD);
    bf16* vT     = alloc((size_t)NHEAD * DV_D * M);
    bf16* a_out  = alloc((size_t)M * NHEAD * DV_D);

    // convert hidden states
    {
        int n = M * HID_D;
        convert_bf16_kernel<<<(n / 4 + 255) / 256, 256, 0, stream>>>(hs, hs_b, n);
    }
    // transpose-convert weights: in (K,N) -> out (N,K)
    dim3 tb(32, 8);
    transpose_convert_kernel<<<dim3(QLR_D / 32, HID_D / 32), tb, 0, stream>>>(w_q_a, wqa_t, HID_D, QLR_D);
    transpose_convert_kernel<<<dim3(KVLR_D / 32, HID_D / 32), tb, 0, stream>>>(w_kv_a, wkva_t, HID_D, KVLR_D);
    transpose_convert_kernel<<<dim3((NHEAD * DN_D) / 32, QLR_D / 32), tb, 0, stream>>>(w_q_nope, wqn_t, QLR_D, NHEAD * DN_D);
    transpose_convert_kernel<<<dim3((NHEAD * DR_D) / 32, QLR_D / 32), tb, 0, stream>>>(w_q_rope, wqr_t, QLR_D, NHEAD * DR_D);
    transpose_convert_kernel<<<dim3((NHEAD * DN_D) / 32, KVLR_D / 32), tb, 0, stream>>>(w_k_nope, wkn_t, KVLR_D, NHEAD * DN_D);
    transpose_convert_kernel<<<dim3((NHEAD * DR_D) / 32, KVLR_D / 32), tb, 0, stream>>>(w_k_rope, wkr_t, KVLR_D, NHEAD * DR_D);
    transpose_convert_kernel<<<dim3((NHEAD * DV_D) / 32, KVLR_D / 32), tb, 0, stream>>>(w_v, wv_t, KVLR_D, NHEAD * DV_D);
    transpose_convert_kernel<<<dim3(HID_D / 32, (NHEAD * DV_D) / 32), tb, 0, stream>>>(w_o, wo_t, NHEAD * DV_D, HID_D);

    // low-rank projections
    gemm_bt_kernel<0><<<dim3(QLR_D / 128, M / 128), 256, 0, stream>>>(hs_b, wqa_t, q_c, M, QLR_D, HID_D, 0, 0);
    gemm_bt_kernel<0><<<dim3(KVLR_D / 128, M / 128), 256, 0, stream>>>(hs_b, wkva_t, kv_c, M, KVLR_D, HID_D, 0, 0);
    // up-projections into fused layouts
    gemm_bt_kernel<2><<<dim3((NHEAD * DN_D) / 128, M / 128), 256, 0, stream>>>(q_c, wqn_t, q_full, M, NHEAD * DN_D, QLR_D, 7, 0);
    gemm_bt_kernel<2><<<dim3((NHEAD * DR_D) / 128, M / 128), 256, 0, stream>>>(q_c, wqr_t, q_full, M, NHEAD * DR_D, QLR_D, 6, 128);
    gemm_bt_kernel<2><<<dim3((NHEAD * DN_D) / 128, M / 128), 256, 0, stream>>>(kv_c, wkn_t, k_full, M, NHEAD * DN_D, KVLR_D, 7, 0);
    gemm_bt_kernel<2><<<dim3((NHEAD * DR_D) / 128, M / 128), 256, 0, stream>>>(kv_c, wkr_t, k_full, M, NHEAD * DR_D, KVLR_D, 6, 128);
    // V, stored transposed (d-major) for attention B-fragments
    gemm_bt_kernel<3><<<dim3((NHEAD * DV_D) / 128, M / 128), 256, 0, stream>>>(kv_c, wv_t, vT, M, NHEAD * DV_D, KVLR_D, 0, 0);

    // rope on fused q/k buffers (cols 128..191 per head)
    {
        int n = M * NHEAD * 32;
        rope_kernel<<<(n + 255) / 256, 256, 0, stream>>>(q_full, M);
        rope_kernel<<<(n + 255) / 256, 256, 0, stream>>>(k_full, M);
    }

    // attention
    attn_kernel<<<dim3(S_LEN / 128, BATCH * NHEAD), 256, 0, stream>>>(q_full, k_full, vT, a_out);

    // output projection (fp32 out)
    gemm_bt_kernel<1><<<dim3(HID_D / 128, M / 128), 256, 0, stream>>>(a_out, wo_t, out, M, HID_D, NHEAD * DV_D, 0, 0);

    (void)in_sizes; (void)n_in; (void)out_size; (void)ws_size;
}

// Round 3
// 511.825 us; speedup vs baseline: 1.9691x; 1.2124x over previous
//
#include <hip/hip_runtime.h>
#include <hip/hip_bf16.h>
#include <stdint.h>

typedef __hip_bfloat16 bf16;
typedef __attribute__((ext_vector_type(8))) short bf16x8;
typedef __attribute__((ext_vector_type(4))) float f32x4;

#define MFMA16(a,b,c) __builtin_amdgcn_mfma_f32_16x16x32_bf16((a),(b),(c),0,0,0)

#define BATCH 2
#define S_LEN 2048
#define HID_D 2048
#define NHEAD 16
#define QLR_D 1536
#define KVLR_D 512
#define DN_D 128
#define DR_D 64
#define DV_D 128
#define QKD 192            // DN + DR
// 1/sqrt(192)
#define ATT_SCALE 0.07216878364870322f

__device__ __forceinline__ void async_load16(const bf16* g, bf16* l) {
    __builtin_amdgcn_global_load_lds((const __attribute__((address_space(1))) uint32_t*)g,
                                     (__attribute__((address_space(3))) uint32_t*)l,
                                     16, 0, 0);
}

__device__ __forceinline__ unsigned short f2bf_bits(float f) {
    bf16 h = __float2bfloat16(f);
    return *reinterpret_cast<unsigned short*>(&h);
}

// ---- DPP 16-lane row reductions (VALU pipe, not LDS pipe like __shfl_xor) ----
template <int CTRL>
__device__ __forceinline__ float dpp_mov(float x) {
    return __builtin_bit_cast(float,
        __builtin_amdgcn_update_dpp(0, __builtin_bit_cast(int, x), CTRL, 0xF, 0xF, true));
}
__device__ __forceinline__ float row_max16(float x) {
    x = fmaxf(x, dpp_mov<0xB1>(x));   // quad_perm [1,0,3,2]  (xor 1)
    x = fmaxf(x, dpp_mov<0x4E>(x));   // quad_perm [2,3,0,1]  (xor 2)
    x = fmaxf(x, dpp_mov<0x124>(x));  // row_ror:4
    x = fmaxf(x, dpp_mov<0x128>(x));  // row_ror:8
    return x;
}
__device__ __forceinline__ float row_sum16(float x) {
    x += dpp_mov<0xB1>(x);
    x += dpp_mov<0x4E>(x);
    x += dpp_mov<0x124>(x);
    x += dpp_mov<0x128>(x);
    return x;
}

// ---------------- elementwise fp32 -> bf16 convert ----------------
__global__ void convert_bf16_kernel(const float* __restrict__ in, bf16* __restrict__ out, int n) {
    int idx = blockIdx.x * blockDim.x + threadIdx.x;
    int i4 = idx * 4;
    if (i4 >= n) return;
    float4 v = *(const float4*)(in + i4);
    ushort4 o;
    o.x = f2bf_bits(v.x);
    o.y = f2bf_bits(v.y);
    o.z = f2bf_bits(v.z);
    o.w = f2bf_bits(v.w);
    *(ushort4*)(out + i4) = o;
}

// ---------------- transpose + convert: in (K x N) fp32 -> out (N x K) bf16 ----------------
__global__ void transpose_convert_kernel(const float* __restrict__ in, bf16* __restrict__ out,
                                         int K, int N) {
    __shared__ float tile[32][33];
    int tx = threadIdx.x;   // 0..31
    int ty = threadIdx.y;   // 0..7
    int n0 = blockIdx.x * 32, k0 = blockIdx.y * 32;
#pragma unroll
    for (int i = 0; i < 4; i++)
        tile[ty + i * 8][tx] = in[(size_t)(k0 + ty + i * 8) * N + n0 + tx];
    __syncthreads();
#pragma unroll
    for (int i = 0; i < 4; i++)
        out[(size_t)(n0 + ty + i * 8) * K + k0 + tx] = __float2bfloat16(tile[tx][ty + i * 8]);
}

// ---------------- GEMM: C(MxN) = A(MxK,row,ld=lda) * Bt(NxK,row)^T ----------------
// MODE 0: bf16 row-major (ld=N).
// MODE 1: fp32 row-major (ld=N).
// MODE 2: fused Q up-proj: col<2048 -> q_full nope slot; col>=2048 -> rope slot.
// MODE 4: fused KV up-proj: col<2048 -> k_full nope; <3072 -> k_full rope;
//         >=3072 -> vT transposed (C2[(col-3072)*M + row], packed 4-row store).
template <int MODE>
__global__ __launch_bounds__(256, 2)
void gemm_bt_kernel(const bf16* __restrict__ A, const bf16* __restrict__ Bt,
                    void* __restrict__ C, void* __restrict__ C2,
                    int M, int N, int K, int lda) {
    __shared__ __align__(16) bf16 As[128 * 64];
    __shared__ __align__(16) bf16 Bs[128 * 64];
    const int tid = threadIdx.x;
    const int wave = tid >> 6, lane = tid & 63;
    const int quad = lane >> 4, l16 = lane & 15;
    const int wm = (wave >> 1) * 64, wn = (wave & 1) * 64;
    const int m0 = blockIdx.y * 128, n0 = blockIdx.x * 128;

    f32x4 acc[4][4];
#pragma unroll
    for (int i = 0; i < 4; i++)
#pragma unroll
        for (int j = 0; j < 4; j++)
            acc[i][j] = (f32x4){0.f, 0.f, 0.f, 0.f};

    const bf16* ga = A + (size_t)m0 * lda;
    const bf16* gb = Bt + (size_t)n0 * K;

    for (int k0 = 0; k0 < K; k0 += 64) {
        __syncthreads();
#pragma unroll
        for (int i = 0; i < 4; i++) {
            int chunk = i * 256 + tid;
            int row = chunk >> 3, cseg = chunk & 7;
            int wbase = i * 256 + wave * 64;
            async_load16(ga + (size_t)row * lda + k0 + cseg * 8, &As[wbase * 8]);
            async_load16(gb + (size_t)row * K + k0 + cseg * 8, &Bs[wbase * 8]);
        }
        __syncthreads();
#pragma unroll
        for (int kk = 0; kk < 64; kk += 32) {
            bf16x8 af[4], bfr[4];
#pragma unroll
            for (int t = 0; t < 4; t++) {
                af[t]  = *(const bf16x8*)&As[(wm + t * 16 + l16) * 64 + kk + quad * 8];
                bfr[t] = *(const bf16x8*)&Bs[(wn + t * 16 + l16) * 64 + kk + quad * 8];
            }
#pragma unroll
            for (int tm = 0; tm < 4; tm++)
#pragma unroll
                for (int tn = 0; tn < 4; tn++)
                    acc[tm][tn] = MFMA16(af[tm], bfr[tn], acc[tm][tn]);
        }
    }
    // epilogue: C/D layout col=lane&15, row=quad*4+reg
#pragma unroll
    for (int tm = 0; tm < 4; tm++)
#pragma unroll
        for (int tn = 0; tn < 4; tn++) {
            const int col = n0 + wn + tn * 16 + l16;
            const int row0 = m0 + wm + tm * 16 + quad * 4;
            if constexpr (MODE == 4) {
                if (n0 >= 3072) {   // vT: packed transposed store
                    ushort4 pk;
                    pk.x = f2bf_bits(acc[tm][tn][0]);
                    pk.y = f2bf_bits(acc[tm][tn][1]);
                    pk.z = f2bf_bits(acc[tm][tn][2]);
                    pk.w = f2bf_bits(acc[tm][tn][3]);
                    *(ushort4*)((bf16*)C2 + (size_t)(col - 3072) * M + row0) = pk;
                    continue;
                }
            }
#pragma unroll
            for (int r = 0; r < 4; r++) {
                const int row = row0 + r;
                const float v = acc[tm][tn][r];
                if constexpr (MODE == 0)
                    ((bf16*)C)[(size_t)row * N + col] = __float2bfloat16(v);
                else if constexpr (MODE == 1)
                    ((float*)C)[(size_t)row * N + col] = v;
                else if constexpr (MODE == 2) {
                    if (n0 < 2048) {
                        int hh = col >> 7, dd = col & 127;
                        ((bf16*)C)[(size_t)row * (NHEAD * QKD) + hh * QKD + dd] =
                            __float2bfloat16(v);
                    } else {
                        int c2 = col - 2048, hh = c2 >> 6, dd = c2 & 63;
                        ((bf16*)C)[(size_t)row * (NHEAD * QKD) + hh * QKD + 128 + dd] =
                            __float2bfloat16(v);
                    }
                } else {  // MODE 4, k_full part
                    if (n0 < 2048) {
                        int hh = col >> 7, dd = col & 127;
                        ((bf16*)C)[(size_t)row * (NHEAD * QKD) + hh * QKD + dd] =
                            __float2bfloat16(v);
                    } else {
                        int c2 = col - 2048, hh = c2 >> 6, dd = c2 & 63;
                        ((bf16*)C)[(size_t)row * (NHEAD * QKD) + hh * QKD + 128 + dd] =
                            __float2bfloat16(v);
                    }
                }
            }
        }
}

// ---------------- RoPE in-place on fused (M, NH, 192) buffer, cols 128..191 ----------------
__global__ void rope_kernel(bf16* __restrict__ buf, int nrows) {
    int idx = blockIdx.x * blockDim.x + threadIdx.x;
    if (idx >= nrows * NHEAD * 32) return;
    int j = idx & 31;
    int h = (idx >> 5) & (NHEAD - 1);
    int row = idx >> 9;          // / (16*32)
    int pos = row & (S_LEN - 1); // row = b*S + s
    float inv = __expf(-(float)j * (9.210340371976184f / 32.f));  // ln(10000)/32
    float f = (float)pos * inv;
    float c = __cosf(f), s = __sinf(f);
    bf16* p = buf + (size_t)row * (NHEAD * QKD) + h * QKD + 128 + j;
    float x1 = __bfloat162float(p[0]);
    float x2 = __bfloat162float(p[32]);
    p[0]  = __float2bfloat16(x1 * c - x2 * s);
    p[32] = __float2bfloat16(x2 * c + x1 * s);
}

// ---------------- flash attention: 128 q-rows/block, Q in regs, DPP softmax ----------------
__global__ __launch_bounds__(256, 2)
void attn_kernel(const bf16* __restrict__ qf_g, const bf16* __restrict__ kf_g,
                 const bf16* __restrict__ vT, bf16* __restrict__ o_out) {
    __shared__ __align__(16) bf16 k_s[64 * QKD];     // 24 KB
    __shared__ __align__(16) bf16 vt_s[128 * 64];    // 16 KB  (d, kv)
    __shared__ __align__(16) bf16 p_s[4 * 32 * 64];  // 16 KB  per-wave 32x64, quad-XOR swizzled

    const int tid = threadIdx.x;
    const int wave = tid >> 6, lane = tid & 63;
    const int quad = lane >> 4, l16 = lane & 15;
    const int qt = gridDim.x - 1 - blockIdx.x;   // longest-first
    const int q0 = qt * 128;
    const int bh = blockIdx.y;
    const int b = bh >> 4, h = bh & 15;
    const int tokbase = b * S_LEN;
    const int M = BATCH * S_LEN;

    // Q fragments in registers: 2 row-tiles x 6 k-chunks
    const int wq = q0 + wave * 32;
    bf16x8 qfr[2][6];
#pragma unroll
    for (int mt = 0; mt < 2; mt++) {
        const bf16* qrow = qf_g + (size_t)(tokbase + wq + mt * 16 + l16) * (NHEAD * QKD)
                                + h * QKD + quad * 8;
#pragma unroll
        for (int kk = 0; kk < 6; kk++)
            qfr[mt][kk] = *(const bf16x8*)(qrow + kk * 32);
    }

    float m_run[2][4], l_run[2][4];
#pragma unroll
    for (int mt = 0; mt < 2; mt++)
#pragma unroll
        for (int r = 0; r < 4; r++) { m_run[mt][r] = -1e30f; l_run[mt][r] = 0.f; }
    f32x4 oacc[2][8];
#pragma unroll
    for (int mt = 0; mt < 2; mt++)
#pragma unroll
        for (int d = 0; d < 8; d++) oacc[mt][d] = (f32x4){0.f, 0.f, 0.f, 0.f};

    const int niter = q0 / 64 + 2;
    for (int it = 0; it < niter; it++) {
        const int kv0 = it * 64;
        __syncthreads();
        // stage K tile: 64 rows x 192 = 1536 16B-chunks, 6 issues
#pragma unroll
        for (int i = 0; i < 6; i++) {
            int c = i * 256 + tid;
            int row = c / 24, seg = c % 24;
            async_load16(kf_g + (size_t)(tokbase + kv0 + row) * (NHEAD * QKD) + h * QKD + seg * 8,
                         &k_s[(i * 256 + wave * 64) * 8]);
        }
        // stage V^T tile: 128 d-rows x 64 kv = 1024 chunks, 4 issues
#pragma unroll
        for (int i = 0; i < 4; i++) {
            int c = i * 256 + tid;
            int d = c >> 3, seg = c & 7;
            async_load16(vT + (size_t)(h * 128 + d) * M + tokbase + kv0 + seg * 8,
                         &vt_s[(i * 256 + wave * 64) * 8]);
        }
        __syncthreads();

        if (kv0 <= wq + 31) {
            const bool do0 = kv0 <= wq + 15;  // mt=0 tile not fully masked
            // S = Q K^T : 2 x (16 x 64)
            f32x4 sa[2][4];
#pragma unroll
            for (int mt = 0; mt < 2; mt++)
#pragma unroll
                for (int nt = 0; nt < 4; nt++) sa[mt][nt] = (f32x4){0.f, 0.f, 0.f, 0.f};
#pragma unroll
            for (int kk = 0; kk < 6; kk++) {
                bf16x8 bk[4];
#pragma unroll
                for (int nt = 0; nt < 4; nt++)
                    bk[nt] = *(const bf16x8*)&k_s[(nt * 16 + l16) * QKD + kk * 32 + quad * 8];
#pragma unroll
                for (int mt = 0; mt < 2; mt++)
#pragma unroll
                    for (int nt = 0; nt < 4; nt++)
                        sa[mt][nt] = MFMA16(qfr[mt][kk], bk[nt], sa[mt][nt]);
            }

            // online softmax + P store (per row-tile) — DPP reductions, VALU pipe
            auto softmax_mt = [&](int mt) {
                const int qmin = wq + mt * 16;
                const bool needMask = (kv0 + 63) > qmin;
                float alpha[4];
#pragma unroll
                for (int r = 0; r < 4; r++) {
                    const int qpos = qmin + quad * 4 + r;
                    float mx = m_run[mt][r];
                    float sv[4];
#pragma unroll
                    for (int nt = 0; nt < 4; nt++) {
                        float x = sa[mt][nt][r];
                        if (needMask && (kv0 + nt * 16 + l16 > qpos)) x = -1e30f;
                        sv[nt] = x;
                        mx = fmaxf(mx, x);
                    }
                    mx = row_max16(mx);
                    float rs = 0.f;
#pragma unroll
                    for (int nt = 0; nt < 4; nt++) {
                        float p = __expf(ATT_SCALE * (sv[nt] - mx));
                        sv[nt] = p;
                        rs += p;
                    }
                    rs = row_sum16(rs);
                    alpha[r] = __expf(ATT_SCALE * (m_run[mt][r] - mx));
                    l_run[mt][r] = alpha[r] * l_run[mt][r] + rs;
                    m_run[mt][r] = mx;
                    // store P, quad-XOR swizzle on 16-col groups (conflict-free)
                    const int row = mt * 16 + quad * 4 + r;
#pragma unroll
                    for (int nt = 0; nt < 4; nt++)
                        p_s[wave * 2048 + row * 64 + ((nt ^ quad) << 4) + l16] =
                            __float2bfloat16(sv[nt]);
                }
#pragma unroll
                for (int d = 0; d < 8; d++)
#pragma unroll
                    for (int r = 0; r < 4; r++) oacc[mt][d][r] *= alpha[r];
            };
            if (do0) softmax_mt(0);
            softmax_mt(1);

            // O += P V : A-frags from swizzled p_s, B-frags from vt_s
#pragma unroll
            for (int kk = 0; kk < 2; kk++) {
                bf16x8 bv[8];
#pragma unroll
                for (int d = 0; d < 8; d++)
                    bv[d] = *(const bf16x8*)&vt_s[(d * 16 + l16) * 64 + kk * 32 + quad * 8];
                const int grp = (kk * 2 + (quad >> 1)) ^ (l16 >> 2);
                const int lo8 = (quad & 1) * 8;
                bf16x8 ap1 = *(const bf16x8*)&p_s[wave * 2048 + (16 + l16) * 64 + (grp << 4) + lo8];
                if (do0) {
                    bf16x8 ap0 = *(const bf16x8*)&p_s[wave * 2048 + l16 * 64 + (grp << 4) + lo8];
#pragma unroll
                    for (int d = 0; d < 8; d++) oacc[0][d] = MFMA16(ap0, bv[d], oacc[0][d]);
                }
#pragma unroll
                for (int d = 0; d < 8; d++) oacc[1][d] = MFMA16(ap1, bv[d], oacc[1][d]);
            }
        }
    }

    // epilogue: divide by l, write (M, NH*128) bf16
#pragma unroll
    for (int mt = 0; mt < 2; mt++)
#pragma unroll
        for (int d = 0; d < 8; d++)
#pragma unroll
            for (int r = 0; r < 4; r++) {
                int qrow = wq + mt * 16 + quad * 4 + r;
                int col = h * DV_D + d * 16 + l16;
                o_out[(size_t)(tokbase + qrow) * (NHEAD * DV_D) + col] =
                    __float2bfloat16(oacc[mt][d][r] / l_run[mt][r]);
            }
}

// ---------------- launch ----------------
extern "C" void kernel_launch(void* const* d_in, const int* in_sizes, int n_in,
                              void* d_out, int out_size, void* d_ws, size_t ws_size,
                              hipStream_t stream) {
    const float* hs        = (const float*)d_in[0];
    const float* w_q_a     = (const float*)d_in[2];
    const float* w_q_nope  = (const float*)d_in[3];
    const float* w_q_rope  = (const float*)d_in[4];
    const float* w_kv_a    = (const float*)d_in[5];
    const float* w_k_nope  = (const float*)d_in[6];
    const float* w_k_rope  = (const float*)d_in[7];
    const float* w_v       = (const float*)d_in[8];
    const float* w_o       = (const float*)d_in[9];
    float* out = (float*)d_out;

    const int M = BATCH * S_LEN;  // 4096

    char* wsp = (char*)d_ws;
    auto alloc = [&](size_t elems) {
        bf16* p = (bf16*)wsp;
        wsp += ((elems * 2 + 255) / 256) * 256;
        return p;
    };
    bf16* hs_b     = alloc((size_t)M * HID_D);
    bf16* w_a_t    = alloc((size_t)2048 * HID_D);          // [q_a(1536) ; kv_a(512)] x 2048
    bf16* wq_up_t  = alloc((size_t)3072 * QLR_D);          // [q_nope(2048) ; q_rope(1024)] x 1536
    bf16* wkv_up_t = alloc((size_t)5120 * KVLR_D);         // [k_nope ; k_rope ; v] x 512
    bf16* wo_t     = alloc((size_t)HID_D * (NHEAD * DV_D));
    bf16* qkv_c    = alloc((size_t)M * 2048);              // [q_c(1536) | kv_c(512)]
    bf16* q_full   = alloc((size_t)M * NHEAD * QKD);
    bf16* k_full   = alloc((size_t)M * NHEAD * QKD);
    bf16* vT       = alloc((size_t)NHEAD * DV_D * M);
    bf16* a_out    = alloc((size_t)M * NHEAD * DV_D);

    // convert hidden states
    {
        int n = M * HID_D;
        convert_bf16_kernel<<<(n / 4 + 255) / 256, 256, 0, stream>>>(hs, hs_b, n);
    }
    // transpose-convert weights into concatenated (N,K) layouts
    dim3 tb(32, 8);
    transpose_convert_kernel<<<dim3(QLR_D / 32, HID_D / 32), tb, 0, stream>>>(w_q_a, w_a_t, HID_D, QLR_D);
    transpose_convert_kernel<<<dim3(KVLR_D / 32, HID_D / 32), tb, 0, stream>>>(w_kv_a, w_a_t + (size_t)QLR_D * HID_D, HID_D, KVLR_D);
    transpose_convert_kernel<<<dim3(2048 / 32, QLR_D / 32), tb, 0, stream>>>(w_q_nope, wq_up_t, QLR_D, 2048);
    transpose_convert_kernel<<<dim3(1024 / 32, QLR_D / 32), tb, 0, stream>>>(w_q_rope, wq_up_t + (size_t)2048 * QLR_D, QLR_D, 1024);
    transpose_convert_kernel<<<dim3(2048 / 32, KVLR_D / 32), tb, 0, stream>>>(w_k_nope, wkv_up_t, KVLR_D, 2048);
    transpose_convert_kernel<<<dim3(1024 / 32, KVLR_D / 32), tb, 0, stream>>>(w_k_rope, wkv_up_t + (size_t)2048 * KVLR_D, KVLR_D, 1024);
    transpose_convert_kernel<<<dim3(2048 / 32, KVLR_D / 32), tb, 0, stream>>>(w_v, wkv_up_t + (size_t)3072 * KVLR_D, KVLR_D, 2048);
    transpose_convert_kernel<<<dim3(HID_D / 32, 2048 / 32), tb, 0, stream>>>(w_o, wo_t, NHEAD * DV_D, HID_D);

    // fused low-rank projection: [q_c | kv_c] = hs @ [w_q_a | w_kv_a]
    gemm_bt_kernel<0><<<dim3(2048 / 128, M / 128), 256, 0, stream>>>(hs_b, w_a_t, qkv_c, nullptr, M, 2048, HID_D, HID_D);
    // fused Q up-projection (nope+rope) into q_full
    gemm_bt_kernel<2><<<dim3(3072 / 128, M / 128), 256, 0, stream>>>(qkv_c, wq_up_t, q_full, nullptr, M, 3072, QLR_D, 2048);
    // fused KV up-projection (k_nope+k_rope+v) into k_full and vT
    gemm_bt_kernel<4><<<dim3(5120 / 128, M / 128), 256, 0, stream>>>(qkv_c + QLR_D, wkv_up_t, k_full, vT, M, 5120, KVLR_D, 2048);

    // rope on fused q/k buffers (cols 128..191 per head)
    {
        int n = M * NHEAD * 32;
        rope_kernel<<<(n + 255) / 256, 256, 0, stream>>>(q_full, M);
        rope_kernel<<<(n + 255) / 256, 256, 0, stream>>>(k_full, M);
    }

    // attention
    attn_kernel<<<dim3(S_LEN / 128, BATCH * NHEAD), 256, 0, stream>>>(q_full, k_full, vT, a_out);

    // output projection (fp32 out)
    gemm_bt_kernel<1><<<dim3(HID_D / 128, M / 128), 256, 0, stream>>>(a_out, wo_t, out, nullptr, M, HID_D, NHEAD * DV_D, NHEAD * DV_D);

    (void)in_sizes; (void)n_in; (void)out_size; (void)ws_size;
}

// Round 4
// 480.459 us; speedup vs baseline: 2.0976x; 1.0653x over previous
//
#include <hip/hip_runtime.h>
#include <hip/hip_bf16.h>
#include <stdint.h>

typedef __hip_bfloat16 bf16;
typedef __attribute__((ext_vector_type(8))) short bf16x8;
typedef __attribute__((ext_vector_type(4))) float f32x4;

#define MFMA16(a,b,c) __builtin_amdgcn_mfma_f32_16x16x32_bf16((a),(b),(c),0,0,0)

#define BATCH 2
#define S_LEN 2048
#define HID_D 2048
#define NHEAD 16
#define QLR_D 1536
#define KVLR_D 512
#define DN_D 128
#define DR_D 64
#define DV_D 128
#define QKD 192            // DN + DR
// 1/sqrt(192)
#define ATT_SCALE 0.07216878364870322f

__device__ __forceinline__ void async_load16(const bf16* g, bf16* l) {
    __builtin_amdgcn_global_load_lds((const __attribute__((address_space(1))) uint32_t*)g,
                                     (__attribute__((address_space(3))) uint32_t*)l,
                                     16, 0, 0);
}

__device__ __forceinline__ unsigned short f2bf_bits(float f) {
    bf16 h = __float2bfloat16(f);
    return *reinterpret_cast<unsigned short*>(&h);
}

// ---- DPP 16-lane row reductions (VALU pipe, not LDS pipe like __shfl_xor) ----
template <int CTRL>
__device__ __forceinline__ float dpp_mov(float x) {
    return __builtin_bit_cast(float,
        __builtin_amdgcn_update_dpp(0, __builtin_bit_cast(int, x), CTRL, 0xF, 0xF, true));
}
__device__ __forceinline__ float row_max16(float x) {
    x = fmaxf(x, dpp_mov<0xB1>(x));   // quad_perm [1,0,3,2]  (xor 1)
    x = fmaxf(x, dpp_mov<0x4E>(x));   // quad_perm [2,3,0,1]  (xor 2)
    x = fmaxf(x, dpp_mov<0x124>(x));  // row_ror:4
    x = fmaxf(x, dpp_mov<0x128>(x));  // row_ror:8
    return x;
}
__device__ __forceinline__ float row_sum16(float x) {
    x += dpp_mov<0xB1>(x);
    x += dpp_mov<0x4E>(x);
    x += dpp_mov<0x124>(x);
    x += dpp_mov<0x128>(x);
    return x;
}

// ---------------- elementwise fp32 -> bf16 convert ----------------
__global__ void convert_bf16_kernel(const float* __restrict__ in, bf16* __restrict__ out, int n) {
    int idx = blockIdx.x * blockDim.x + threadIdx.x;
    int i4 = idx * 4;
    if (i4 >= n) return;
    float4 v = *(const float4*)(in + i4);
    ushort4 o;
    o.x = f2bf_bits(v.x);
    o.y = f2bf_bits(v.y);
    o.z = f2bf_bits(v.z);
    o.w = f2bf_bits(v.w);
    *(ushort4*)(out + i4) = o;
}

// ---------------- transpose + convert: in (K x N) fp32 -> out (N x K) bf16 ----------------
__global__ void transpose_convert_kernel(const float* __restrict__ in, bf16* __restrict__ out,
                                         int K, int N) {
    __shared__ float tile[32][33];
    int tx = threadIdx.x;   // 0..31
    int ty = threadIdx.y;   // 0..7
    int n0 = blockIdx.x * 32, k0 = blockIdx.y * 32;
#pragma unroll
    for (int i = 0; i < 4; i++)
        tile[ty + i * 8][tx] = in[(size_t)(k0 + ty + i * 8) * N + n0 + tx];
    __syncthreads();
#pragma unroll
    for (int i = 0; i < 4; i++)
        out[(size_t)(n0 + ty + i * 8) * K + k0 + tx] = __float2bfloat16(tile[tx][ty + i * 8]);
}

// ---------------- GEMM: C(MxN) = A(MxK,row,ld=lda) * Bt(NxK,row)^T ----------------
// MODE 0: bf16 row-major (ld=N).
// MODE 1: fp32 row-major (ld=N).
// MODE 2: fused Q up-proj: col<2048 -> q_full nope slot; col>=2048 -> rope slot.
// MODE 4: fused KV up-proj: col<2048 -> k_full nope; <3072 -> k_full rope;
//         >=3072 -> vT transposed (C2[(col-3072)*M + row], packed 4-row store).
template <int MODE>
__global__ __launch_bounds__(256, 2)
void gemm_bt_kernel(const bf16* __restrict__ A, const bf16* __restrict__ Bt,
                    void* __restrict__ C, void* __restrict__ C2,
                    int M, int N, int K, int lda) {
    __shared__ __align__(16) bf16 As[128 * 64];
    __shared__ __align__(16) bf16 Bs[128 * 64];
    const int tid = threadIdx.x;
    const int wave = tid >> 6, lane = tid & 63;
    const int quad = lane >> 4, l16 = lane & 15;
    const int wm = (wave >> 1) * 64, wn = (wave & 1) * 64;
    const int m0 = blockIdx.y * 128, n0 = blockIdx.x * 128;

    f32x4 acc[4][4];
#pragma unroll
    for (int i = 0; i < 4; i++)
#pragma unroll
        for (int j = 0; j < 4; j++)
            acc[i][j] = (f32x4){0.f, 0.f, 0.f, 0.f};

    const bf16* ga = A + (size_t)m0 * lda;
    const bf16* gb = Bt + (size_t)n0 * K;

    for (int k0 = 0; k0 < K; k0 += 64) {
        __syncthreads();
#pragma unroll
        for (int i = 0; i < 4; i++) {
            int chunk = i * 256 + tid;
            int row = chunk >> 3, cseg = chunk & 7;
            int wbase = i * 256 + wave * 64;
            async_load16(ga + (size_t)row * lda + k0 + cseg * 8, &As[wbase * 8]);
            async_load16(gb + (size_t)row * K + k0 + cseg * 8, &Bs[wbase * 8]);
        }
        __syncthreads();
#pragma unroll
        for (int kk = 0; kk < 64; kk += 32) {
            bf16x8 af[4], bfr[4];
#pragma unroll
            for (int t = 0; t < 4; t++) {
                af[t]  = *(const bf16x8*)&As[(wm + t * 16 + l16) * 64 + kk + quad * 8];
                bfr[t] = *(const bf16x8*)&Bs[(wn + t * 16 + l16) * 64 + kk + quad * 8];
            }
#pragma unroll
            for (int tm = 0; tm < 4; tm++)
#pragma unroll
                for (int tn = 0; tn < 4; tn++)
                    acc[tm][tn] = MFMA16(af[tm], bfr[tn], acc[tm][tn]);
        }
    }
    // epilogue: C/D layout col=lane&15, row=quad*4+reg
#pragma unroll
    for (int tm = 0; tm < 4; tm++)
#pragma unroll
        for (int tn = 0; tn < 4; tn++) {
            const int col = n0 + wn + tn * 16 + l16;
            const int row0 = m0 + wm + tm * 16 + quad * 4;
            if constexpr (MODE == 4) {
                if (n0 >= 3072) {   // vT: packed transposed store
                    ushort4 pk;
                    pk.x = f2bf_bits(acc[tm][tn][0]);
                    pk.y = f2bf_bits(acc[tm][tn][1]);
                    pk.z = f2bf_bits(acc[tm][tn][2]);
                    pk.w = f2bf_bits(acc[tm][tn][3]);
                    *(ushort4*)((bf16*)C2 + (size_t)(col - 3072) * M + row0) = pk;
                    continue;
                }
            }
#pragma unroll
            for (int r = 0; r < 4; r++) {
                const int row = row0 + r;
                const float v = acc[tm][tn][r];
                if constexpr (MODE == 0)
                    ((bf16*)C)[(size_t)row * N + col] = __float2bfloat16(v);
                else if constexpr (MODE == 1)
                    ((float*)C)[(size_t)row * N + col] = v;
                else if constexpr (MODE == 2) {
                    if (n0 < 2048) {
                        int hh = col >> 7, dd = col & 127;
                        ((bf16*)C)[(size_t)row * (NHEAD * QKD) + hh * QKD + dd] =
                            __float2bfloat16(v);
                    } else {
                        int c2 = col - 2048, hh = c2 >> 6, dd = c2 & 63;
                        ((bf16*)C)[(size_t)row * (NHEAD * QKD) + hh * QKD + 128 + dd] =
                            __float2bfloat16(v);
                    }
                } else {  // MODE 4, k_full part
                    if (n0 < 2048) {
                        int hh = col >> 7, dd = col & 127;
                        ((bf16*)C)[(size_t)row * (NHEAD * QKD) + hh * QKD + dd] =
                            __float2bfloat16(v);
                    } else {
                        int c2 = col - 2048, hh = c2 >> 6, dd = c2 & 63;
                        ((bf16*)C)[(size_t)row * (NHEAD * QKD) + hh * QKD + 128 + dd] =
                            __float2bfloat16(v);
                    }
                }
            }
        }
}

// ---------------- RoPE in-place on fused (M, NH, 192) buffer, cols 128..191 ----------------
__global__ void rope_kernel(bf16* __restrict__ buf, int nrows) {
    int idx = blockIdx.x * blockDim.x + threadIdx.x;
    if (idx >= nrows * NHEAD * 32) return;
    int j = idx & 31;
    int h = (idx >> 5) & (NHEAD - 1);
    int row = idx >> 9;          // / (16*32)
    int pos = row & (S_LEN - 1); // row = b*S + s
    float inv = __expf(-(float)j * (9.210340371976184f / 32.f));  // ln(10000)/32
    float f = (float)pos * inv;
    float c = __cosf(f), s = __sinf(f);
    bf16* p = buf + (size_t)row * (NHEAD * QKD) + h * QKD + 128 + j;
    float x1 = __bfloat162float(p[0]);
    float x2 = __bfloat162float(p[32]);
    p[0]  = __float2bfloat16(x1 * c - x2 * s);
    p[32] = __float2bfloat16(x2 * c + x1 * s);
}

// ---------------- flash attention: 128 q-rows/block, Q in regs, DPP softmax ----------------
// Pair-balanced schedule: co-resident blocks g and g+256 (same x, bh +/- 16) get
// complementary causal lengths so each CU's total work is ~constant.
__global__ __launch_bounds__(256, 2)
void attn_kernel(const bf16* __restrict__ qf_g, const bf16* __restrict__ kf_g,
                 const bf16* __restrict__ vT, bf16* __restrict__ o_out) {
    __shared__ __align__(16) bf16 k_s[64 * QKD];     // 24 KB
    __shared__ __align__(16) bf16 vt_s[128 * 64];    // 16 KB  (d, kv)
    __shared__ __align__(16) bf16 p_s[4 * 32 * 64];  // 16 KB  per-wave 32x64, quad-XOR swizzled

    const int tid = threadIdx.x;
    const int wave = tid >> 6, lane = tid & 63;
    const int quad = lane >> 4, l16 = lane & 15;
    const int bh = blockIdx.y;
    // complementary pairing: bh<16 gets (15-x), bh>=16 gets x  -> pair sums to 15
    const int qt = (bh < 16) ? (gridDim.x - 1 - blockIdx.x) : blockIdx.x;
    const int q0 = qt * 128;
    const int b = bh >> 4, h = bh & 15;
    const int tokbase = b * S_LEN;
    const int M = BATCH * S_LEN;

    // Q fragments in registers: 2 row-tiles x 6 k-chunks
    const int wq = q0 + wave * 32;
    bf16x8 qfr[2][6];
#pragma unroll
    for (int mt = 0; mt < 2; mt++) {
        const bf16* qrow = qf_g + (size_t)(tokbase + wq + mt * 16 + l16) * (NHEAD * QKD)
                                + h * QKD + quad * 8;
#pragma unroll
        for (int kk = 0; kk < 6; kk++)
            qfr[mt][kk] = *(const bf16x8*)(qrow + kk * 32);
    }

    float m_run[2][4], l_run[2][4];
#pragma unroll
    for (int mt = 0; mt < 2; mt++)
#pragma unroll
        for (int r = 0; r < 4; r++) { m_run[mt][r] = -1e30f; l_run[mt][r] = 0.f; }
    f32x4 oacc[2][8];
#pragma unroll
    for (int mt = 0; mt < 2; mt++)
#pragma unroll
        for (int d = 0; d < 8; d++) oacc[mt][d] = (f32x4){0.f, 0.f, 0.f, 0.f};

    const int niter = q0 / 64 + 2;
    for (int it = 0; it < niter; it++) {
        const int kv0 = it * 64;
        __syncthreads();
        // stage K tile: 64 rows x 192 = 1536 16B-chunks, 6 issues
#pragma unroll
        for (int i = 0; i < 6; i++) {
            int c = i * 256 + tid;
            int row = c / 24, seg = c % 24;
            async_load16(kf_g + (size_t)(tokbase + kv0 + row) * (NHEAD * QKD) + h * QKD + seg * 8,
                         &k_s[(i * 256 + wave * 64) * 8]);
        }
        // stage V^T tile: 128 d-rows x 64 kv = 1024 chunks, 4 issues
#pragma unroll
        for (int i = 0; i < 4; i++) {
            int c = i * 256 + tid;
            int d = c >> 3, seg = c & 7;
            async_load16(vT + (size_t)(h * 128 + d) * M + tokbase + kv0 + seg * 8,
                         &vt_s[(i * 256 + wave * 64) * 8]);
        }
        __syncthreads();

        if (kv0 <= wq + 31) {
            const bool do0 = kv0 <= wq + 15;  // mt=0 tile not fully masked
            // S = Q K^T : 2 x (16 x 64)
            f32x4 sa[2][4];
#pragma unroll
            for (int mt = 0; mt < 2; mt++)
#pragma unroll
                for (int nt = 0; nt < 4; nt++) sa[mt][nt] = (f32x4){0.f, 0.f, 0.f, 0.f};
#pragma unroll
            for (int kk = 0; kk < 6; kk++) {
                bf16x8 bk[4];
#pragma unroll
                for (int nt = 0; nt < 4; nt++)
                    bk[nt] = *(const bf16x8*)&k_s[(nt * 16 + l16) * QKD + kk * 32 + quad * 8];
#pragma unroll
                for (int mt = 0; mt < 2; mt++)
#pragma unroll
                    for (int nt = 0; nt < 4; nt++)
                        sa[mt][nt] = MFMA16(qfr[mt][kk], bk[nt], sa[mt][nt]);
            }

            // online softmax + P store (per row-tile) — DPP reductions, VALU pipe
            auto softmax_mt = [&](int mt) {
                const int qmin = wq + mt * 16;
                const bool needMask = (kv0 + 63) > qmin;
                float alpha[4];
#pragma unroll
                for (int r = 0; r < 4; r++) {
                    const int qpos = qmin + quad * 4 + r;
                    float mx = m_run[mt][r];
                    float sv[4];
#pragma unroll
                    for (int nt = 0; nt < 4; nt++) {
                        float x = sa[mt][nt][r];
                        if (needMask && (kv0 + nt * 16 + l16 > qpos)) x = -1e30f;
                        sv[nt] = x;
                        mx = fmaxf(mx, x);
                    }
                    mx = row_max16(mx);
                    float rs = 0.f;
#pragma unroll
                    for (int nt = 0; nt < 4; nt++) {
                        float p = __expf(ATT_SCALE * (sv[nt] - mx));
                        sv[nt] = p;
                        rs += p;
                    }
                    rs = row_sum16(rs);
                    alpha[r] = __expf(ATT_SCALE * (m_run[mt][r] - mx));
                    l_run[mt][r] = alpha[r] * l_run[mt][r] + rs;
                    m_run[mt][r] = mx;
                    // store P, quad-XOR swizzle on 16-col groups (conflict-free)
                    const int row = mt * 16 + quad * 4 + r;
#pragma unroll
                    for (int nt = 0; nt < 4; nt++)
                        p_s[wave * 2048 + row * 64 + ((nt ^ quad) << 4) + l16] =
                            __float2bfloat16(sv[nt]);
                }
#pragma unroll
                for (int d = 0; d < 8; d++)
#pragma unroll
                    for (int r = 0; r < 4; r++) oacc[mt][d][r] *= alpha[r];
            };
            if (do0) softmax_mt(0);
            softmax_mt(1);

            // O += P V : A-frags from swizzled p_s, B-frags from vt_s
#pragma unroll
            for (int kk = 0; kk < 2; kk++) {
                bf16x8 bv[8];
#pragma unroll
                for (int d = 0; d < 8; d++)
                    bv[d] = *(const bf16x8*)&vt_s[(d * 16 + l16) * 64 + kk * 32 + quad * 8];
                const int grp = (kk * 2 + (quad >> 1)) ^ (l16 >> 2);
                const int lo8 = (quad & 1) * 8;
                bf16x8 ap1 = *(const bf16x8*)&p_s[wave * 2048 + (16 + l16) * 64 + (grp << 4) + lo8];
                if (do0) {
                    bf16x8 ap0 = *(const bf16x8*)&p_s[wave * 2048 + l16 * 64 + (grp << 4) + lo8];
#pragma unroll
                    for (int d = 0; d < 8; d++) oacc[0][d] = MFMA16(ap0, bv[d], oacc[0][d]);
                }
#pragma unroll
                for (int d = 0; d < 8; d++) oacc[1][d] = MFMA16(ap1, bv[d], oacc[1][d]);
            }
        }
    }

    // epilogue: divide by l, write (M, NH*128) bf16
#pragma unroll
    for (int mt = 0; mt < 2; mt++)
#pragma unroll
        for (int d = 0; d < 8; d++)
#pragma unroll
            for (int r = 0; r < 4; r++) {
                int qrow = wq + mt * 16 + quad * 4 + r;
                int col = h * DV_D + d * 16 + l16;
                o_out[(size_t)(tokbase + qrow) * (NHEAD * DV_D) + col] =
                    __float2bfloat16(oacc[mt][d][r] / l_run[mt][r]);
            }
}

// ---------------- launch ----------------
extern "C" void kernel_launch(void* const* d_in, const int* in_sizes, int n_in,
                              void* d_out, int out_size, void* d_ws, size_t ws_size,
                              hipStream_t stream) {
    const float* hs        = (const float*)d_in[0];
    const float* w_q_a     = (const float*)d_in[2];
    const float* w_q_nope  = (const float*)d_in[3];
    const float* w_q_rope  = (const float*)d_in[4];
    const float* w_kv_a    = (const float*)d_in[5];
    const float* w_k_nope  = (const float*)d_in[6];
    const float* w_k_rope  = (const float*)d_in[7];
    const float* w_v       = (const float*)d_in[8];
    const float* w_o       = (const float*)d_in[9];
    float* out = (float*)d_out;

    const int M = BATCH * S_LEN;  // 4096

    char* wsp = (char*)d_ws;
    auto alloc = [&](size_t elems) {
        bf16* p = (bf16*)wsp;
        wsp += ((elems * 2 + 255) / 256) * 256;
        return p;
    };
    bf16* hs_b     = alloc((size_t)M * HID_D);
    bf16* w_a_t    = alloc((size_t)2048 * HID_D);          // [q_a(1536) ; kv_a(512)] x 2048
    bf16* wq_up_t  = alloc((size_t)3072 * QLR_D);          // [q_nope(2048) ; q_rope(1024)] x 1536
    bf16* wkv_up_t = alloc((size_t)5120 * KVLR_D);         // [k_nope ; k_rope ; v] x 512
    bf16* wo_t     = alloc((size_t)HID_D * (NHEAD * DV_D));
    bf16* qkv_c    = alloc((size_t)M * 2048);              // [q_c(1536) | kv_c(512)]
    bf16* q_full   = alloc((size_t)M * NHEAD * QKD);
    bf16* k_full   = alloc((size_t)M * NHEAD * QKD);
    bf16* vT       = alloc((size_t)NHEAD * DV_D * M);
    bf16* a_out    = alloc((size_t)M * NHEAD * DV_D);

    // convert hidden states
    {
        int n = M * HID_D;
        convert_bf16_kernel<<<(n / 4 + 255) / 256, 256, 0, stream>>>(hs, hs_b, n);
    }
    // transpose-convert weights into concatenated (N,K) layouts
    dim3 tb(32, 8);
    transpose_convert_kernel<<<dim3(QLR_D / 32, HID_D / 32), tb, 0, stream>>>(w_q_a, w_a_t, HID_D, QLR_D);
    transpose_convert_kernel<<<dim3(KVLR_D / 32, HID_D / 32), tb, 0, stream>>>(w_kv_a, w_a_t + (size_t)QLR_D * HID_D, HID_D, KVLR_D);
    transpose_convert_kernel<<<dim3(2048 / 32, QLR_D / 32), tb, 0, stream>>>(w_q_nope, wq_up_t, QLR_D, 2048);
    transpose_convert_kernel<<<dim3(1024 / 32, QLR_D / 32), tb, 0, stream>>>(w_q_rope, wq_up_t + (size_t)2048 * QLR_D, QLR_D, 1024);
    transpose_convert_kernel<<<dim3(2048 / 32, KVLR_D / 32), tb, 0, stream>>>(w_k_nope, wkv_up_t, KVLR_D, 2048);
    transpose_convert_kernel<<<dim3(1024 / 32, KVLR_D / 32), tb, 0, stream>>>(w_k_rope, wkv_up_t + (size_t)2048 * KVLR_D, KVLR_D, 1024);
    transpose_convert_kernel<<<dim3(2048 / 32, KVLR_D / 32), tb, 0, stream>>>(w_v, wkv_up_t + (size_t)3072 * KVLR_D, KVLR_D, 2048);
    transpose_convert_kernel<<<dim3(HID_D / 32, 2048 / 32), tb, 0, stream>>>(w_o, wo_t, NHEAD * DV_D, HID_D);

    // fused low-rank projection: [q_c | kv_c] = hs @ [w_q_a | w_kv_a]
    gemm_bt_kernel<0><<<dim3(2048 / 128, M / 128), 256, 0, stream>>>(hs_b, w_a_t, qkv_c, nullptr, M, 2048, HID_D, HID_D);
    // fused Q up-projection (nope+rope) into q_full
    gemm_bt_kernel<2><<<dim3(3072 / 128, M / 128), 256, 0, stream>>>(qkv_c, wq_up_t, q_full, nullptr, M, 3072, QLR_D, 2048);
    // fused KV up-projection (k_nope+k_rope+v) into k_full and vT
    gemm_bt_kernel<4><<<dim3(5120 / 128, M / 128), 256, 0, stream>>>(qkv_c + QLR_D, wkv_up_t, k_full, vT, M, 5120, KVLR_D, 2048);

    // rope on fused q/k buffers (cols 128..191 per head)
    {
        int n = M * NHEAD * 32;
        rope_kernel<<<(n + 255) / 256, 256, 0, stream>>>(q_full, M);
        rope_kernel<<<(n + 255) / 256, 256, 0, stream>>>(k_full, M);
    }

    // attention
    attn_kernel<<<dim3(S_LEN / 128, BATCH * NHEAD), 256, 0, stream>>>(q_full, k_full, vT, a_out);

    // output projection (fp32 out)
    gemm_bt_kernel<1><<<dim3(HID_D / 128, M / 128), 256, 0, stream>>>(a_out, wo_t, out, nullptr, M, HID_D, NHEAD * DV_D, NHEAD * DV_D);

    (void)in_sizes; (void)n_in; (void)out_size; (void)ws_size;
}